// Round 21
// baseline (544.876 us; speedup 1.0000x reference)
//
#include <hip/hip_runtime.h>

#define BN_EPS 1e-5f

typedef __attribute__((ext_vector_type(8))) short bf16x8;
typedef __attribute__((ext_vector_type(4))) float f32x4;

__device__ __forceinline__ unsigned short f32_to_bf16(float f) {
    unsigned u = __float_as_uint(f);
    u += 0x7fffu + ((u >> 16) & 1u);   // round to nearest even
    return (unsigned short)(u >> 16);
}
__device__ __forceinline__ float bf16_lo(unsigned v) { return __uint_as_float(v << 16); }
__device__ __forceinline__ float bf16_hi(unsigned v) { return __uint_as_float(v & 0xffff0000u); }

#define EW_SCALE (1.0f / 32767.0f)

// ===========================================================================
// CSR construction (by dst): rank pass (fused into layer-1 gemm) ->
// scan (2 kernels) -> atomic-free fill.  einfo packed 4B: (src<<15) | ew_q15
// ===========================================================================
__global__ __launch_bounds__(256) void scan_part1(
    const int* __restrict__ deg, int* __restrict__ blockSums, int N)
{
    __shared__ int sm[256];
    int t = threadIdx.x;
    int i0 = blockIdx.x * 512 + t * 2;
    int a = (i0     < N) ? deg[i0]     : 0;
    int b = (i0 + 1 < N) ? deg[i0 + 1] : 0;
    sm[t] = a + b;
    __syncthreads();
    for (int off = 128; off > 0; off >>= 1) {
        if (t < off) sm[t] += sm[t + off];
        __syncthreads();
    }
    if (t == 0) blockSums[blockIdx.x] = sm[0];
}

__global__ __launch_bounds__(256) void scan_part3(
    const int* __restrict__ deg, const int* __restrict__ blockSums,
    int* __restrict__ row_start, int NB, int N, int E)
{
    __shared__ int sb[256];
    __shared__ int sm[256];
    int t = threadIdx.x;

    sb[t] = (t < NB) ? blockSums[t] : 0;
    __syncthreads();
    for (int off = 1; off < 256; off <<= 1) {
        int v = (t >= off) ? sb[t - off] : 0;
        __syncthreads();
        sb[t] += v;
        __syncthreads();
    }
    const int boff = (blockIdx.x > 0) ? sb[blockIdx.x - 1] : 0;

    int i0 = blockIdx.x * 512 + t * 2;
    int a = (i0     < N) ? deg[i0]     : 0;
    int b = (i0 + 1 < N) ? deg[i0 + 1] : 0;
    sm[t] = a + b;
    __syncthreads();
    for (int off = 1; off < 256; off <<= 1) {
        int v = (t >= off) ? sm[t - off] : 0;
        __syncthreads();
        sm[t] += v;
        __syncthreads();
    }
    int excl = boff + ((t > 0) ? sm[t - 1] : 0);
    if (i0 < N)     row_start[i0]     = excl;
    if (i0 + 1 < N) row_start[i0 + 1] = excl + a;
    if (blockIdx.x == 0 && t == 0) row_start[N] = E;
}

__global__ __launch_bounds__(256) void fill_pass2(
    const int* __restrict__ src, const int* __restrict__ dst,
    const float* __restrict__ ew, const int* __restrict__ rank,
    const int* __restrict__ row_start, unsigned* __restrict__ einfo, int E)
{
    int i = blockIdx.x * 256 + threadIdx.x;
    if (i < E) {
        int pos = row_start[dst[i]] + rank[i];
        unsigned q = (unsigned)__float2int_rn(ew[i] * 32767.0f);
        einfo[pos] = ((unsigned)src[i] << 15) | q;
    }
}

// ===========================================================================
// Pack Wa weights into MFMA B-frag layout (bf16); zero-init deg and stats.
// wf: [0,8192) = W1a (KS=4); then per layer i: 8192 + i*4096 = Wsa_i (KS=2).
// ===========================================================================
__global__ __launch_bounds__(256) void prep_wfrag(
    const float* __restrict__ W1a, const float* __restrict__ Wsa,
    unsigned short* __restrict__ wf, int* __restrict__ deg,
    float* __restrict__ stats3, int N, int nW)
{
    int z = blockIdx.x * 256 + threadIdx.x;
    if (z < N) deg[z] = 0;
    if (z < 384) stats3[z] = 0.f;

    int bid = blockIdx.x;
    if (bid >= nW) return;
    const float* src; unsigned short* dst; int KS, chunk;
    if (bid < 4) { src = W1a; dst = wf; KS = 4; chunk = bid; }
    else {
        int t = bid - 4;
        int layer = t >> 1;
        chunk = t & 1;
        src = Wsa + (size_t)layer * 4096;
        dst = wf + 8192 + layer * 4096;
        KS = 2;
    }
    int base = chunk * 2048;
    for (int e = base + threadIdx.x; e < base + 2048; e += 256) {
        int j  = e & 7;
        int l  = (e >> 3) & 63;
        int nk = e >> 9;
        int ks = nk % KS, n = nk / KS;
        int k  = ks * 32 + ((l >> 4) << 3) + j;
        int c  = n * 16 + (l & 15);
        dst[e] = f32_to_bf16(src[k * 64 + c]);
    }
}

// ===========================================================================
// MFMA GEMM (+ optional fused rank pass on tail blocks).
// MODE 0: A f32 -> bf16-packed out (gather table).
// MODE 2: A = f32 h2; fused BN(statsIn,g,be)+ReLU(+res) in staging; layer
//         output written to hout (f32) AND bf16-packed out for the gather.
// B-fragments read from global (L2-hot).
// ===========================================================================
template<int KS, int MODE>
__global__ __launch_bounds__(256) void gemm_mfma(
    const void* __restrict__ Ain, const unsigned short* __restrict__ wfrag,
    void* __restrict__ out,
    const float* __restrict__ statsIn, const float* __restrict__ g,
    const float* __restrict__ be, const float* __restrict__ res,
    float* __restrict__ hout, int N,
    const int* __restrict__ rdst, int* __restrict__ rdeg,
    int* __restrict__ rrank, int rE, int gblocks)
{
    constexpr int K   = KS * 32;
    constexpr int LDA = K + 8;
    __shared__ __align__(16) unsigned short sA[64 * LDA];
    __shared__ float sab[128];

    const int tid = threadIdx.x;
    if ((int)blockIdx.x >= gblocks) {          // rank blocks (tail indices)
        int i = (blockIdx.x - gblocks) * 256 + tid;
        if (i < rE) rrank[i] = atomicAdd(&rdeg[rdst[i]], 1);
        return;
    }
    const int bid = blockIdx.x;

    if (MODE == 2) {
        if (tid < 64) {
            float invN = 1.0f / (float)N;
            float mean = statsIn[tid] * invN;
            float var  = statsIn[64 + tid] * invN - mean * mean;
            float a = g[tid] * rsqrtf(var + BN_EPS);
            sab[tid]      = a;
            sab[64 + tid] = be[tid] - mean * a;
        }
        __syncthreads();
    }

    const int w  = tid >> 6;
    const int l  = tid & 63;
    const int lr = l & 15;
    const int lg = l >> 4;
    const int ntiles = (N + 63) >> 6;
    const bf16x8* wg = (const bf16x8*)wfrag;

    for (int tile = bid; tile < ntiles; tile += gblocks) {
        const int r0 = tile * 64;

        {
            const float* Af = (const float*)Ain;
            constexpr int C4 = K / 4;
            for (int i = tid; i < 64 * C4; i += 256) {
                int r = i / C4, c4 = i % C4;
                int gr = r0 + r;
                float4 v = make_float4(0.f, 0.f, 0.f, 0.f);
                if (gr < N) {
                    v = reinterpret_cast<const float4*>(Af + (size_t)gr * K)[c4];
                    if (MODE == 2) {
                        int l0 = c4 * 4;
                        v.x = fmaxf(fmaf(v.x, sab[l0 + 0], sab[64 + l0 + 0]), 0.f);
                        v.y = fmaxf(fmaf(v.y, sab[l0 + 1], sab[64 + l0 + 1]), 0.f);
                        v.z = fmaxf(fmaf(v.z, sab[l0 + 2], sab[64 + l0 + 2]), 0.f);
                        v.w = fmaxf(fmaf(v.w, sab[l0 + 3], sab[64 + l0 + 3]), 0.f);
                        if (res) {
                            float4 rv = reinterpret_cast<const float4*>(res + (size_t)gr * K)[c4];
                            v.x += rv.x; v.y += rv.y; v.z += rv.z; v.w += rv.w;
                        }
                        reinterpret_cast<float4*>(hout + (size_t)gr * K)[c4] = v;
                    }
                }
                ushort4 pk;
                pk.x = f32_to_bf16(v.x); pk.y = f32_to_bf16(v.y);
                pk.z = f32_to_bf16(v.z); pk.w = f32_to_bf16(v.w);
                *reinterpret_cast<ushort4*>(&sA[r * LDA + c4 * 4]) = pk;
            }
        }
        __syncthreads();

        f32x4 acc0 = {0.f,0.f,0.f,0.f}, acc1 = {0.f,0.f,0.f,0.f};
        f32x4 acc2 = {0.f,0.f,0.f,0.f}, acc3 = {0.f,0.f,0.f,0.f};

        #pragma unroll
        for (int ks = 0; ks < KS; ++ks) {
            bf16x8 af = *reinterpret_cast<const bf16x8*>(
                &sA[(w * 16 + lr) * LDA + ks * 32 + lg * 8]);
            bf16x8 b0 = wg[(0 * KS + ks) * 64 + l];
            bf16x8 b1 = wg[(1 * KS + ks) * 64 + l];
            bf16x8 b2 = wg[(2 * KS + ks) * 64 + l];
            bf16x8 b3 = wg[(3 * KS + ks) * 64 + l];
            acc0 = __builtin_amdgcn_mfma_f32_16x16x32_bf16(af, b0, acc0, 0, 0, 0);
            acc1 = __builtin_amdgcn_mfma_f32_16x16x32_bf16(af, b1, acc1, 0, 0, 0);
            acc2 = __builtin_amdgcn_mfma_f32_16x16x32_bf16(af, b2, acc2, 0, 0, 0);
            acc3 = __builtin_amdgcn_mfma_f32_16x16x32_bf16(af, b3, acc3, 0, 0, 0);
        }

        const int rlocal = w * 16 + lg * 4;
        float v[4][4];
        #pragma unroll
        for (int n = 0; n < 4; ++n) {
            f32x4 a = (n == 0) ? acc0 : (n == 1) ? acc1 : (n == 2) ? acc2 : acc3;
            #pragma unroll
            for (int j = 0; j < 4; ++j) v[n][j] = a[j];
        }

        __syncthreads();   // all waves done reading sA

        // bf16-packed coalesced epilogue through sA (stride 72)
        #pragma unroll
        for (int n = 0; n < 4; ++n)
            #pragma unroll
            for (int j = 0; j < 4; ++j)
                sA[(rlocal + j) * 72 + n * 16 + lr] = f32_to_bf16(v[n][j]);
        __syncthreads();
        unsigned short* o = (unsigned short*)out;
        for (int i = tid; i < 64 * 8; i += 256) {
            int r = i >> 3, q = i & 7;
            if (r0 + r < N)
                *reinterpret_cast<uint4*>(o + (size_t)(r0 + r) * 64 + q * 8) =
                    *reinterpret_cast<const uint4*>(&sA[r * 72 + q * 8]);
        }
        __syncthreads();   // protect sA before next tile's staging
    }
}

// ===========================================================================
// Fused gather-aggregate + MLP-2nd-layer + BN stats:
//   mid[r] = relu((1+eps)*y[r] + sum_j w_j*y[src_j] + ba)     (in-wave)
//   h2[r]  = mid[r] @ Wb + bb                                 (VALU, LDS bcast)
//   stats += {sum, sumsq}(h2)
// Quarter-wave (16 lanes x uint2 = 128B) per edge, 16-edge unroll.
// After shfl reduce every lane holds the full row -> wave-local Wb product.
// ===========================================================================
__global__ __launch_bounds__(256) void agg_mlp_kernel(
    const unsigned* __restrict__ yu,
    const int* __restrict__ row_start,
    const unsigned* __restrict__ einfo,
    const float* __restrict__ epsp,
    const float* __restrict__ ba,
    const float* __restrict__ Wb,    // f32 [64][64] (k-major)
    const float* __restrict__ bb,
    float* __restrict__ h2out,
    float* __restrict__ statsOut, int N)
{
    __shared__ float sWb[64 * 64];
    __shared__ float rowbuf[4][64];
    __shared__ float sred[4][64];

    const int tid  = threadIdx.x;
    const int lane = tid & 63;
    const int wid  = tid >> 6;
    const int q    = lane >> 4;
    const int u    = lane & 15;

    for (int i = tid; i < 1024; i += 256)
        reinterpret_cast<float4*>(sWb)[i] = reinterpret_cast<const float4*>(Wb)[i];
    __syncthreads();

    int w  = (blockIdx.x * 256 + tid) >> 6;
    const int nw = (gridDim.x * 256) >> 6;
    const float eps1 = 1.0f + epsp[0];
    const float4 bal = *reinterpret_cast<const float4*>(ba + 4 * u);
    const float bb_l = bb[lane];

    float csA = 0.f, cqA = 0.f;

    for (int r = w; r < N; r += nw) {
        const int rs = row_start[r];
        const int re = row_start[r + 1];

        float A0=0.f,A1=0.f,A2=0.f,A3=0.f, B0=0.f,B1=0.f,B2=0.f,B3=0.f;
        float C0=0.f,C1=0.f,C2=0.f,C3=0.f, D0=0.f,D1=0.f,D2=0.f,D3=0.f;
        int j = rs;
        for (; j + 16 <= re; j += 16) {
            const int b = j + q * 4;
            unsigned p0 = einfo[b + 0], p1 = einfo[b + 1];
            unsigned p2 = einfo[b + 2], p3 = einfo[b + 3];
            uint2 y0 = *reinterpret_cast<const uint2*>(&yu[(size_t)(p0 >> 15) * 32 + 2 * u]);
            uint2 y1 = *reinterpret_cast<const uint2*>(&yu[(size_t)(p1 >> 15) * 32 + 2 * u]);
            uint2 y2 = *reinterpret_cast<const uint2*>(&yu[(size_t)(p2 >> 15) * 32 + 2 * u]);
            uint2 y3 = *reinterpret_cast<const uint2*>(&yu[(size_t)(p3 >> 15) * 32 + 2 * u]);
            float w0 = (float)(p0 & 0x7FFFu) * EW_SCALE;
            float w1 = (float)(p1 & 0x7FFFu) * EW_SCALE;
            float w2 = (float)(p2 & 0x7FFFu) * EW_SCALE;
            float w3 = (float)(p3 & 0x7FFFu) * EW_SCALE;
            A0 = fmaf(w0, bf16_lo(y0.x), A0); A1 = fmaf(w0, bf16_hi(y0.x), A1);
            A2 = fmaf(w0, bf16_lo(y0.y), A2); A3 = fmaf(w0, bf16_hi(y0.y), A3);
            B0 = fmaf(w1, bf16_lo(y1.x), B0); B1 = fmaf(w1, bf16_hi(y1.x), B1);
            B2 = fmaf(w1, bf16_lo(y1.y), B2); B3 = fmaf(w1, bf16_hi(y1.y), B3);
            C0 = fmaf(w2, bf16_lo(y2.x), C0); C1 = fmaf(w2, bf16_hi(y2.x), C1);
            C2 = fmaf(w2, bf16_lo(y2.y), C2); C3 = fmaf(w2, bf16_hi(y2.y), C3);
            D0 = fmaf(w3, bf16_lo(y3.x), D0); D1 = fmaf(w3, bf16_hi(y3.x), D1);
            D2 = fmaf(w3, bf16_lo(y3.y), D2); D3 = fmaf(w3, bf16_hi(y3.y), D3);
        }
        for (; j + 4 <= re; j += 4) {
            unsigned p = einfo[j + q];
            uint2 y = *reinterpret_cast<const uint2*>(&yu[(size_t)(p >> 15) * 32 + 2 * u]);
            float wv = (float)(p & 0x7FFFu) * EW_SCALE;
            A0 = fmaf(wv, bf16_lo(y.x), A0); A1 = fmaf(wv, bf16_hi(y.x), A1);
            A2 = fmaf(wv, bf16_lo(y.y), A2); A3 = fmaf(wv, bf16_hi(y.y), A3);
        }
        if (j < re) {
            int e = j + q;
            bool valid = e < re;
            unsigned p = einfo[valid ? e : rs];
            float wv = valid ? (float)(p & 0x7FFFu) * EW_SCALE : 0.f;
            uint2 y = *reinterpret_cast<const uint2*>(&yu[(size_t)(p >> 15) * 32 + 2 * u]);
            B0 = fmaf(wv, bf16_lo(y.x), B0); B1 = fmaf(wv, bf16_hi(y.x), B1);
            B2 = fmaf(wv, bf16_lo(y.y), B2); B3 = fmaf(wv, bf16_hi(y.y), B3);
        }
        float s0 = (A0 + B0) + (C0 + D0);
        float s1 = (A1 + B1) + (C1 + D1);
        float s2 = (A2 + B2) + (C2 + D2);
        float s3 = (A3 + B3) + (C3 + D3);
        s0 += __shfl_xor(s0, 16); s0 += __shfl_xor(s0, 32);
        s1 += __shfl_xor(s1, 16); s1 += __shfl_xor(s1, 32);
        s2 += __shfl_xor(s2, 16); s2 += __shfl_xor(s2, 32);
        s3 += __shfl_xor(s3, 16); s3 += __shfl_xor(s3, 32);

        uint2 sv = *reinterpret_cast<const uint2*>(&yu[(size_t)r * 32 + 2 * u]);
        float m0 = fmaxf(fmaf(eps1, bf16_lo(sv.x), s0) + bal.x, 0.f);
        float m1 = fmaxf(fmaf(eps1, bf16_hi(sv.x), s1) + bal.y, 0.f);
        float m2 = fmaxf(fmaf(eps1, bf16_lo(sv.y), s2) + bal.z, 0.f);
        float m3 = fmaxf(fmaf(eps1, bf16_hi(sv.y), s3) + bal.w, 0.f);

        if (q == 0)
            *reinterpret_cast<float4*>(&rowbuf[wid][4 * u]) =
                make_float4(m0, m1, m2, m3);
        // wave-local LDS write->read: compiler orders via lgkmcnt (same wave)

        float acc = bb_l;
        #pragma unroll 4
        for (int k = 0; k < 64; k += 4) {
            float4 m = *reinterpret_cast<const float4*>(&rowbuf[wid][k]); // broadcast
            acc = fmaf(m.x, sWb[(k + 0) * 64 + lane], acc);
            acc = fmaf(m.y, sWb[(k + 1) * 64 + lane], acc);
            acc = fmaf(m.z, sWb[(k + 2) * 64 + lane], acc);
            acc = fmaf(m.w, sWb[(k + 3) * 64 + lane], acc);
        }
        h2out[(size_t)r * 64 + lane] = acc;
        csA += acc;
        cqA += acc * acc;
    }

    __syncthreads();
    sred[wid][lane] = csA;
    __syncthreads();
    if (tid < 64) {
        float s = sred[0][tid] + sred[1][tid] + sred[2][tid] + sred[3][tid];
        atomicAdd(&statsOut[tid], s);
    }
    __syncthreads();
    sred[wid][lane] = cqA;
    __syncthreads();
    if (tid < 64) {
        float qq = sred[0][tid] + sred[1][tid] + sred[2][tid] + sred[3][tid];
        atomicAdd(&statsOut[64 + tid], qq);
    }
}

// ===========================================================================
// Final BN apply with fused finalize (+ReLU, optional residual)
// ===========================================================================
template<int RES>
__global__ __launch_bounds__(256) void bn_apply(
    const float* __restrict__ h2, const float* __restrict__ stats,
    const float* __restrict__ g, const float* __restrict__ be,
    const float* res, float* out, int N, int n4)
{
    __shared__ float sab[128];
    int t = threadIdx.x;
    if (t < 64) {
        float invN = 1.0f / (float)N;
        float mean = stats[t] * invN;
        float var  = stats[64 + t] * invN - mean * mean;
        float a = g[t] * rsqrtf(var + BN_EPS);
        sab[t]      = a;
        sab[64 + t] = be[t] - mean * a;
    }
    __syncthreads();

    int i = blockIdx.x * blockDim.x + t;
    int stride = gridDim.x * blockDim.x;
    for (; i < n4; i += stride) {
        float4 v = reinterpret_cast<const float4*>(h2)[i];
        int l0 = (i * 4) & 63;
        float4 o;
        o.x = fmaxf(fmaf(v.x, sab[l0 + 0], sab[64 + l0 + 0]), 0.f);
        o.y = fmaxf(fmaf(v.y, sab[l0 + 1], sab[64 + l0 + 1]), 0.f);
        o.z = fmaxf(fmaf(v.z, sab[l0 + 2], sab[64 + l0 + 2]), 0.f);
        o.w = fmaxf(fmaf(v.w, sab[l0 + 3], sab[64 + l0 + 3]), 0.f);
        if (RES) {
            float4 rv = reinterpret_cast<const float4*>(res)[i];
            o.x += rv.x; o.y += rv.y; o.z += rv.z; o.w += rv.w;
        }
        reinterpret_cast<float4*>(out)[i] = o;
    }
}

// ===========================================================================
extern "C" void kernel_launch(void* const* d_in, const int* in_sizes, int n_in,
                              void* d_out, int out_size, void* d_ws, size_t ws_size,
                              hipStream_t stream)
{
    const float* x    = (const float*)d_in[0];
    const int*   ei   = (const int*)  d_in[1];
    const float* ew   = (const float*)d_in[2];
    const float* eps1 = (const float*)d_in[3];
    const float* W1a  = (const float*)d_in[4];
    const float* b1a  = (const float*)d_in[5];
    const float* W1b  = (const float*)d_in[6];
    const float* b1b  = (const float*)d_in[7];
    const float* g1   = (const float*)d_in[8];
    const float* be1  = (const float*)d_in[9];
    const float* epss = (const float*)d_in[10];
    const float* Wsa  = (const float*)d_in[11];
    const float* bsa  = (const float*)d_in[12];
    const float* Wsb  = (const float*)d_in[13];
    const float* bsb  = (const float*)d_in[14];
    const float* gs   = (const float*)d_in[15];
    const float* bes  = (const float*)d_in[16];

    const int N   = in_sizes[0] / 128;
    const int E   = in_sizes[2];
    const int Lm1 = in_sizes[10];
    const int* src  = ei;
    const int* dstp = ei + E;

    // ---- workspace layout ----
    char* ws = (char*)d_ws;
    size_t off = 0;
    unsigned* einfo = (unsigned*)(ws + off); off += (size_t)E * 4;
    float* regA  = (float*)(ws + off);   off += (size_t)N * 128 * 4;
    unsigned* ybf = (unsigned*)(ws + off); off += (size_t)N * 32 * 4;
    int*   rank  = (int*)  (ws + off);   off += (size_t)E * 4;
    int*   deg   = (int*)  (ws + off);   off += (size_t)N * 4;
    int*   row_start = (int*)(ws + off); off += (size_t)(N + 1) * 4;
    float* stats3 = (float*)(ws + off);  off += 384 * 4;
    int*   blockSums = (int*)(ws + off); off += 256 * 4;
    off = (off + 15) & ~(size_t)15;
    unsigned short* wf = (unsigned short*)(ws + off);
    float* outp  = (float*)d_out;
    float* bufY  = regA;                                   // h2 scratch (N*64 f32)

    const int n4   = N * 64 / 4;
    const int NB   = (N + 511) / 512;
    const int EB   = (E + 255) / 256;
    const int nW   = 4 + 2 * Lm1;
    const int PREP_B = (N + 255) / 256;
    const int NT   = (N + 63) / 64;

    prep_wfrag<<<PREP_B, 256, 0, stream>>>(W1a, Wsa, wf, deg, stats3, N, nW);

    // ---- layer-1 gemm (x @ W1a -> ybf) FUSED with CSR rank pass ----
    gemm_mfma<4, 0><<<1024 + EB, 256, 0, stream>>>(
        x, wf, ybf, nullptr, nullptr, nullptr, nullptr, nullptr, N,
        dstp, deg, rank, E, 1024);

    // ---- CSR scan + fill ----
    scan_part1<<<NB, 256, 0, stream>>>(deg, blockSums, N);
    scan_part3<<<NB, 256, 0, stream>>>(deg, blockSums, row_start, NB, N, E);
    fill_pass2<<<EB, 256, 0, stream>>>(src, dstp, ew, rank, row_start, einfo, E);

    // ---- layer 1: fused gather + Wb MLP + stats ----
    agg_mlp_kernel<<<2048, 256, 0, stream>>>(
        ybf, row_start, einfo, eps1, b1a, W1b, b1b, bufY, stats3, N);

    // ---- layers 2..L: MODE2 gemm (BN(prev)+ReLU(+res) fused) + agg_mlp ----
    const float* pg  = g1;
    const float* pbe = be1;
    const float* resp = nullptr;
    for (int i = 0; i < Lm1; ++i) {
        const unsigned short* wfAi = wf + 8192 + i * 4096;
        gemm_mfma<2, 2><<<NT, 256, 0, stream>>>(
            bufY, wfAi, ybf, stats3 + i * 128, pg, pbe, resp, outp, N,
            nullptr, nullptr, nullptr, 0, NT);
        agg_mlp_kernel<<<2048, 256, 0, stream>>>(
            ybf, row_start, einfo, epss + i, bsa + (size_t)i * 64,
            Wsb + (size_t)i * 64 * 64, bsb + (size_t)i * 64,
            bufY, stats3 + (i + 1) * 128, N);
        pg  = gs  + (size_t)i * 64;
        pbe = bes + (size_t)i * 64;
        resp = outp;
    }

    // ---- final BN apply ----
    if (Lm1 > 0)
        bn_apply<1><<<2048, 256, 0, stream>>>(bufY, stats3 + Lm1 * 128, pg, pbe, outp, outp, N, n4);
    else
        bn_apply<0><<<2048, 256, 0, stream>>>(bufY, stats3, pg, pbe, nullptr, outp, N, n4);
}

// Round 22
// 452.540 us; speedup vs baseline: 1.2040x; 1.2040x over previous
//
#include <hip/hip_runtime.h>

#define BN_EPS 1e-5f

typedef __attribute__((ext_vector_type(8))) short bf16x8;
typedef __attribute__((ext_vector_type(4))) float f32x4;

__device__ __forceinline__ unsigned short f32_to_bf16(float f) {
    unsigned u = __float_as_uint(f);
    u += 0x7fffu + ((u >> 16) & 1u);   // round to nearest even
    return (unsigned short)(u >> 16);
}
__device__ __forceinline__ float bf16_lo(unsigned v) { return __uint_as_float(v << 16); }
__device__ __forceinline__ float bf16_hi(unsigned v) { return __uint_as_float(v & 0xffff0000u); }

#define EW_SCALE (1.0f / 32767.0f)

// ===========================================================================
// CSR construction (by dst): rank pass (fused into layer-1 gemm) ->
// scan (2 kernels) -> atomic-free fill.  einfo packed 4B: (src<<15) | ew_q15
// ===========================================================================
__global__ __launch_bounds__(256) void scan_part1(
    const int* __restrict__ deg, int* __restrict__ blockSums, int N)
{
    __shared__ int sm[256];
    int t = threadIdx.x;
    int i0 = blockIdx.x * 512 + t * 2;
    int a = (i0     < N) ? deg[i0]     : 0;
    int b = (i0 + 1 < N) ? deg[i0 + 1] : 0;
    sm[t] = a + b;
    __syncthreads();
    for (int off = 128; off > 0; off >>= 1) {
        if (t < off) sm[t] += sm[t + off];
        __syncthreads();
    }
    if (t == 0) blockSums[blockIdx.x] = sm[0];
}

__global__ __launch_bounds__(256) void scan_part3(
    const int* __restrict__ deg, const int* __restrict__ blockSums,
    int* __restrict__ row_start, int NB, int N, int E)
{
    __shared__ int sb[256];
    __shared__ int sm[256];
    int t = threadIdx.x;

    sb[t] = (t < NB) ? blockSums[t] : 0;
    __syncthreads();
    for (int off = 1; off < 256; off <<= 1) {
        int v = (t >= off) ? sb[t - off] : 0;
        __syncthreads();
        sb[t] += v;
        __syncthreads();
    }
    const int boff = (blockIdx.x > 0) ? sb[blockIdx.x - 1] : 0;

    int i0 = blockIdx.x * 512 + t * 2;
    int a = (i0     < N) ? deg[i0]     : 0;
    int b = (i0 + 1 < N) ? deg[i0 + 1] : 0;
    sm[t] = a + b;
    __syncthreads();
    for (int off = 1; off < 256; off <<= 1) {
        int v = (t >= off) ? sm[t - off] : 0;
        __syncthreads();
        sm[t] += v;
        __syncthreads();
    }
    int excl = boff + ((t > 0) ? sm[t - 1] : 0);
    if (i0 < N)     row_start[i0]     = excl;
    if (i0 + 1 < N) row_start[i0 + 1] = excl + a;
    if (blockIdx.x == 0 && t == 0) row_start[N] = E;
}

__global__ __launch_bounds__(256) void fill_pass2(
    const int* __restrict__ src, const int* __restrict__ dst,
    const float* __restrict__ ew, const int* __restrict__ rank,
    const int* __restrict__ row_start, unsigned* __restrict__ einfo, int E)
{
    int i = blockIdx.x * 256 + threadIdx.x;
    if (i < E) {
        int pos = row_start[dst[i]] + rank[i];
        unsigned q = (unsigned)__float2int_rn(ew[i] * 32767.0f);
        einfo[pos] = ((unsigned)src[i] << 15) | q;
    }
}

// ===========================================================================
// Pack weights into MFMA B-frag layout (bf16); zero-init deg and stats.
// ===========================================================================
__global__ __launch_bounds__(256) void prep_wfrag(
    const float* __restrict__ W1a, const float* __restrict__ W1b,
    const float* __restrict__ Wsa, const float* __restrict__ Wsb,
    unsigned short* __restrict__ wf, int* __restrict__ deg,
    float* __restrict__ stats3, int N, int nW)
{
    int z = blockIdx.x * 256 + threadIdx.x;
    if (z < N) deg[z] = 0;
    if (z < 384) stats3[z] = 0.f;

    int bid = blockIdx.x;
    if (bid >= nW) return;
    const float* src; unsigned short* dst; int KS, chunk;
    if (bid < 4)      { src = W1a; dst = wf;        KS = 4; chunk = bid; }
    else if (bid < 6) { src = W1b; dst = wf + 8192; KS = 2; chunk = bid - 4; }
    else {
        int t = bid - 6;
        int layer = t >> 2;
        int wh = (t >> 1) & 1;
        chunk = t & 1;
        src = (wh ? Wsb : Wsa) + (size_t)layer * 4096;
        dst = wf + 12288 + layer * 8192 + wh * 4096;
        KS = 2;
    }
    int base = chunk * 2048;
    for (int e = base + threadIdx.x; e < base + 2048; e += 256) {
        int j  = e & 7;
        int l  = (e >> 3) & 63;
        int nk = e >> 9;
        int ks = nk % KS, n = nk / KS;
        int k  = ks * 32 + ((l >> 4) << 3) + j;
        int c  = n * 16 + (l & 15);
        dst[e] = f32_to_bf16(src[k * 64 + c]);
    }
}

// ===========================================================================
// Persistent multi-tile MFMA GEMM (+ optional fused rank pass).
// GEMM blocks are blockIdx < gblocks (scheduled FIRST); rank blocks follow.
// B-fragments read from global (L2-hot). Stats in registers across tiles,
// one atomic round per block after the tile loop.
// MODE 0: A f32. MODE 1: A packed bf16. MODE 2: fused BN+ReLU(+res) staging.
// ===========================================================================
template<int KS, int MODE, bool BF16OUT, bool STATS>
__global__ __launch_bounds__(256) void gemm_mfma(
    const void* __restrict__ Ain, const unsigned short* __restrict__ wfrag,
    const float* __restrict__ bias, void* __restrict__ out,
    float* __restrict__ statsOut,
    const float* __restrict__ statsIn, const float* __restrict__ g,
    const float* __restrict__ be, const float* __restrict__ res,
    float* __restrict__ hout, int N,
    const int* __restrict__ rdst, int* __restrict__ rdeg,
    int* __restrict__ rrank, int rE, int gblocks)
{
    constexpr int K   = KS * 32;
    constexpr int LDA = K + 8;
    __shared__ __align__(16) unsigned short sA[64 * LDA];
    __shared__ float sab[128];

    const int tid = threadIdx.x;
    if ((int)blockIdx.x >= gblocks) {          // rank blocks (tail indices)
        int i = (blockIdx.x - gblocks) * 256 + tid;
        if (i < rE) rrank[i] = atomicAdd(&rdeg[rdst[i]], 1);
        return;
    }
    const int bid = blockIdx.x;

    if (MODE == 2) {
        if (tid < 64) {
            float invN = 1.0f / (float)N;
            float mean = statsIn[tid] * invN;
            float var  = statsIn[64 + tid] * invN - mean * mean;
            float a = g[tid] * rsqrtf(var + BN_EPS);
            sab[tid]      = a;
            sab[64 + tid] = be[tid] - mean * a;
        }
        __syncthreads();
    }

    const int w  = tid >> 6;
    const int l  = tid & 63;
    const int lr = l & 15;
    const int lg = l >> 4;
    const int ntiles = (N + 63) >> 6;
    const bf16x8* wg = (const bf16x8*)wfrag;

    float csAcc[4] = {0.f, 0.f, 0.f, 0.f};
    float cqAcc[4] = {0.f, 0.f, 0.f, 0.f};

    for (int tile = bid; tile < ntiles; tile += gblocks) {
        const int r0 = tile * 64;

        if (MODE == 1) {
            const uint4* Au = (const uint4*)Ain;
            constexpr int C16 = K / 8;
            for (int i = tid; i < 64 * C16; i += 256) {
                int r = i / C16, c = i % C16;
                uint4 v = make_uint4(0u, 0u, 0u, 0u);
                if (r0 + r < N) v = Au[(size_t)(r0 + r) * C16 + c];
                *reinterpret_cast<uint4*>(&sA[r * LDA + c * 8]) = v;
            }
        } else {
            const float* Af = (const float*)Ain;
            constexpr int C4 = K / 4;
            for (int i = tid; i < 64 * C4; i += 256) {
                int r = i / C4, c4 = i % C4;
                int gr = r0 + r;
                float4 v = make_float4(0.f, 0.f, 0.f, 0.f);
                if (gr < N) {
                    v = reinterpret_cast<const float4*>(Af + (size_t)gr * K)[c4];
                    if (MODE == 2) {
                        int l0 = c4 * 4;
                        v.x = fmaxf(fmaf(v.x, sab[l0 + 0], sab[64 + l0 + 0]), 0.f);
                        v.y = fmaxf(fmaf(v.y, sab[l0 + 1], sab[64 + l0 + 1]), 0.f);
                        v.z = fmaxf(fmaf(v.z, sab[l0 + 2], sab[64 + l0 + 2]), 0.f);
                        v.w = fmaxf(fmaf(v.w, sab[l0 + 3], sab[64 + l0 + 3]), 0.f);
                        if (res) {
                            float4 rv = reinterpret_cast<const float4*>(res + (size_t)gr * K)[c4];
                            v.x += rv.x; v.y += rv.y; v.z += rv.z; v.w += rv.w;
                        }
                        reinterpret_cast<float4*>(hout + (size_t)gr * K)[c4] = v;
                    }
                }
                ushort4 pk;
                pk.x = f32_to_bf16(v.x); pk.y = f32_to_bf16(v.y);
                pk.z = f32_to_bf16(v.z); pk.w = f32_to_bf16(v.w);
                *reinterpret_cast<ushort4*>(&sA[r * LDA + c4 * 4]) = pk;
            }
        }
        __syncthreads();

        f32x4 acc0 = {0.f,0.f,0.f,0.f}, acc1 = {0.f,0.f,0.f,0.f};
        f32x4 acc2 = {0.f,0.f,0.f,0.f}, acc3 = {0.f,0.f,0.f,0.f};

        #pragma unroll
        for (int ks = 0; ks < KS; ++ks) {
            bf16x8 af = *reinterpret_cast<const bf16x8*>(
                &sA[(w * 16 + lr) * LDA + ks * 32 + lg * 8]);
            bf16x8 b0 = wg[(0 * KS + ks) * 64 + l];
            bf16x8 b1 = wg[(1 * KS + ks) * 64 + l];
            bf16x8 b2 = wg[(2 * KS + ks) * 64 + l];
            bf16x8 b3 = wg[(3 * KS + ks) * 64 + l];
            acc0 = __builtin_amdgcn_mfma_f32_16x16x32_bf16(af, b0, acc0, 0, 0, 0);
            acc1 = __builtin_amdgcn_mfma_f32_16x16x32_bf16(af, b1, acc1, 0, 0, 0);
            acc2 = __builtin_amdgcn_mfma_f32_16x16x32_bf16(af, b2, acc2, 0, 0, 0);
            acc3 = __builtin_amdgcn_mfma_f32_16x16x32_bf16(af, b3, acc3, 0, 0, 0);
        }

        const int rlocal = w * 16 + lg * 4;
        float v[4][4];
        #pragma unroll
        for (int n = 0; n < 4; ++n) {
            float bv = bias ? bias[n * 16 + lr] : 0.f;
            f32x4 a = (n == 0) ? acc0 : (n == 1) ? acc1 : (n == 2) ? acc2 : acc3;
            #pragma unroll
            for (int j = 0; j < 4; ++j) {
                float vv = a[j] + bv;
                v[n][j] = vv;
                if (STATS && (r0 + rlocal + j < N)) {
                    csAcc[n] += vv; cqAcc[n] += vv * vv;
                }
            }
        }

        __syncthreads();   // all waves done reading sA

        if (BF16OUT) {
            #pragma unroll
            for (int n = 0; n < 4; ++n)
                #pragma unroll
                for (int j = 0; j < 4; ++j)
                    sA[(rlocal + j) * 72 + n * 16 + lr] = f32_to_bf16(v[n][j]);
            __syncthreads();
            unsigned short* o = (unsigned short*)out;
            for (int i = tid; i < 64 * 8; i += 256) {
                int r = i >> 3, q = i & 7;
                if (r0 + r < N)
                    *reinterpret_cast<uint4*>(o + (size_t)(r0 + r) * 64 + q * 8) =
                        *reinterpret_cast<const uint4*>(&sA[r * 72 + q * 8]);
            }
        } else {
            float* o = (float*)out;
            float* sAf = reinterpret_cast<float*>(sA);
            #pragma unroll
            for (int half = 0; half < 2; ++half) {
                if ((w >> 1) == half) {
                    #pragma unroll
                    for (int n = 0; n < 4; ++n)
                        #pragma unroll
                        for (int j = 0; j < 4; ++j)
                            sAf[((w & 1) * 16 + lg * 4 + j) * 68 + n * 16 + lr] = v[n][j];
                }
                __syncthreads();
                for (int i = tid; i < 32 * 16; i += 256) {
                    int r = i >> 4, c4 = i & 15;
                    int gr = r0 + half * 32 + r;
                    if (gr < N)
                        *reinterpret_cast<float4*>(o + (size_t)gr * 64 + c4 * 4) =
                            *reinterpret_cast<const float4*>(&sAf[r * 68 + c4 * 4]);
                }
                __syncthreads();
            }
        }
        __syncthreads();   // protect sA before next tile's staging
    }

    if (STATS) {
        float* red = reinterpret_cast<float*>(sA);
        int gg = w * 4 + lg;
        #pragma unroll
        for (int n = 0; n < 4; ++n) red[gg * 64 + n * 16 + lr] = csAcc[n];
        __syncthreads();
        if (tid < 64) {
            float s = 0.f;
            #pragma unroll
            for (int g2 = 0; g2 < 16; ++g2) s += red[g2 * 64 + tid];
            atomicAdd(&statsOut[tid], s);
        }
        __syncthreads();
        #pragma unroll
        for (int n = 0; n < 4; ++n) red[gg * 64 + n * 16 + lr] = cqAcc[n];
        __syncthreads();
        if (tid < 64) {
            float q = 0.f;
            #pragma unroll
            for (int g2 = 0; g2 < 16; ++g2) q += red[g2 * 64 + tid];
            atomicAdd(&statsOut[64 + tid], q);
        }
    }
}

// ===========================================================================
// Gather-aggregate: quarter-wave (16 lanes x uint2 = 128B) per edge,
// 16-edge unroll => 16 outstanding gathers per wave.
// ===========================================================================
__global__ __launch_bounds__(256) void aggmid_kernel(
    const unsigned* __restrict__ yu,
    const int* __restrict__ row_start,
    const unsigned* __restrict__ einfo,
    const float* __restrict__ epsp,
    const float* __restrict__ ba,
    unsigned* __restrict__ midu, int N)
{
    const int lane = threadIdx.x & 63;
    const int q    = lane >> 4;
    const int u    = lane & 15;
    int w  = (blockIdx.x * 256 + threadIdx.x) >> 6;
    const int nw = (gridDim.x * 256) >> 6;
    const float eps1 = 1.0f + epsp[0];
    const float4 bal = *reinterpret_cast<const float4*>(ba + 4 * u);

    for (int r = w; r < N; r += nw) {
        const int rs = row_start[r];
        const int re = row_start[r + 1];

        float A0=0.f,A1=0.f,A2=0.f,A3=0.f, B0=0.f,B1=0.f,B2=0.f,B3=0.f;
        float C0=0.f,C1=0.f,C2=0.f,C3=0.f, D0=0.f,D1=0.f,D2=0.f,D3=0.f;
        int j = rs;
        for (; j + 16 <= re; j += 16) {
            const int b = j + q * 4;
            unsigned p0 = einfo[b + 0], p1 = einfo[b + 1];
            unsigned p2 = einfo[b + 2], p3 = einfo[b + 3];
            uint2 y0 = *reinterpret_cast<const uint2*>(&yu[(size_t)(p0 >> 15) * 32 + 2 * u]);
            uint2 y1 = *reinterpret_cast<const uint2*>(&yu[(size_t)(p1 >> 15) * 32 + 2 * u]);
            uint2 y2 = *reinterpret_cast<const uint2*>(&yu[(size_t)(p2 >> 15) * 32 + 2 * u]);
            uint2 y3 = *reinterpret_cast<const uint2*>(&yu[(size_t)(p3 >> 15) * 32 + 2 * u]);
            float w0 = (float)(p0 & 0x7FFFu) * EW_SCALE;
            float w1 = (float)(p1 & 0x7FFFu) * EW_SCALE;
            float w2 = (float)(p2 & 0x7FFFu) * EW_SCALE;
            float w3 = (float)(p3 & 0x7FFFu) * EW_SCALE;
            A0 = fmaf(w0, bf16_lo(y0.x), A0); A1 = fmaf(w0, bf16_hi(y0.x), A1);
            A2 = fmaf(w0, bf16_lo(y0.y), A2); A3 = fmaf(w0, bf16_hi(y0.y), A3);
            B0 = fmaf(w1, bf16_lo(y1.x), B0); B1 = fmaf(w1, bf16_hi(y1.x), B1);
            B2 = fmaf(w1, bf16_lo(y1.y), B2); B3 = fmaf(w1, bf16_hi(y1.y), B3);
            C0 = fmaf(w2, bf16_lo(y2.x), C0); C1 = fmaf(w2, bf16_hi(y2.x), C1);
            C2 = fmaf(w2, bf16_lo(y2.y), C2); C3 = fmaf(w2, bf16_hi(y2.y), C3);
            D0 = fmaf(w3, bf16_lo(y3.x), D0); D1 = fmaf(w3, bf16_hi(y3.x), D1);
            D2 = fmaf(w3, bf16_lo(y3.y), D2); D3 = fmaf(w3, bf16_hi(y3.y), D3);
        }
        for (; j + 4 <= re; j += 4) {
            unsigned p = einfo[j + q];
            uint2 y = *reinterpret_cast<const uint2*>(&yu[(size_t)(p >> 15) * 32 + 2 * u]);
            float wv = (float)(p & 0x7FFFu) * EW_SCALE;
            A0 = fmaf(wv, bf16_lo(y.x), A0); A1 = fmaf(wv, bf16_hi(y.x), A1);
            A2 = fmaf(wv, bf16_lo(y.y), A2); A3 = fmaf(wv, bf16_hi(y.y), A3);
        }
        if (j < re) {
            int e = j + q;
            bool valid = e < re;
            unsigned p = einfo[valid ? e : rs];
            float wv = valid ? (float)(p & 0x7FFFu) * EW_SCALE : 0.f;
            uint2 y = *reinterpret_cast<const uint2*>(&yu[(size_t)(p >> 15) * 32 + 2 * u]);
            B0 = fmaf(wv, bf16_lo(y.x), B0); B1 = fmaf(wv, bf16_hi(y.x), B1);
            B2 = fmaf(wv, bf16_lo(y.y), B2); B3 = fmaf(wv, bf16_hi(y.y), B3);
        }
        float s0 = (A0 + B0) + (C0 + D0);
        float s1 = (A1 + B1) + (C1 + D1);
        float s2 = (A2 + B2) + (C2 + D2);
        float s3 = (A3 + B3) + (C3 + D3);
        s0 += __shfl_xor(s0, 16); s0 += __shfl_xor(s0, 32);
        s1 += __shfl_xor(s1, 16); s1 += __shfl_xor(s1, 32);
        s2 += __shfl_xor(s2, 16); s2 += __shfl_xor(s2, 32);
        s3 += __shfl_xor(s3, 16); s3 += __shfl_xor(s3, 32);

        uint2 sv = *reinterpret_cast<const uint2*>(&yu[(size_t)r * 32 + 2 * u]);
        float m0 = fmaf(eps1, bf16_lo(sv.x), s0) + bal.x;
        float m1 = fmaf(eps1, bf16_hi(sv.x), s1) + bal.y;
        float m2 = fmaf(eps1, bf16_lo(sv.y), s2) + bal.z;
        float m3 = fmaf(eps1, bf16_hi(sv.y), s3) + bal.w;
        if (q == 0) {
            uint2 pk;
            pk.x = (unsigned)f32_to_bf16(fmaxf(m0, 0.f))
                 | ((unsigned)f32_to_bf16(fmaxf(m1, 0.f)) << 16);
            pk.y = (unsigned)f32_to_bf16(fmaxf(m2, 0.f))
                 | ((unsigned)f32_to_bf16(fmaxf(m3, 0.f)) << 16);
            *reinterpret_cast<uint2*>(&midu[(size_t)r * 32 + 2 * u]) = pk;
        }
    }
}

// ===========================================================================
// Final BN apply with fused finalize (+ReLU, optional residual)
// ===========================================================================
template<int RES>
__global__ __launch_bounds__(256) void bn_apply(
    const float* __restrict__ h2, const float* __restrict__ stats,
    const float* __restrict__ g, const float* __restrict__ be,
    const float* res, float* out, int N, int n4)
{
    __shared__ float sab[128];
    int t = threadIdx.x;
    if (t < 64) {
        float invN = 1.0f / (float)N;
        float mean = stats[t] * invN;
        float var  = stats[64 + t] * invN - mean * mean;
        float a = g[t] * rsqrtf(var + BN_EPS);
        sab[t]      = a;
        sab[64 + t] = be[t] - mean * a;
    }
    __syncthreads();

    int i = blockIdx.x * blockDim.x + t;
    int stride = gridDim.x * blockDim.x;
    for (; i < n4; i += stride) {
        float4 v = reinterpret_cast<const float4*>(h2)[i];
        int l0 = (i * 4) & 63;
        float4 o;
        o.x = fmaxf(fmaf(v.x, sab[l0 + 0], sab[64 + l0 + 0]), 0.f);
        o.y = fmaxf(fmaf(v.y, sab[l0 + 1], sab[64 + l0 + 1]), 0.f);
        o.z = fmaxf(fmaf(v.z, sab[l0 + 2], sab[64 + l0 + 2]), 0.f);
        o.w = fmaxf(fmaf(v.w, sab[l0 + 3], sab[64 + l0 + 3]), 0.f);
        if (RES) {
            float4 rv = reinterpret_cast<const float4*>(res)[i];
            o.x += rv.x; o.y += rv.y; o.z += rv.z; o.w += rv.w;
        }
        reinterpret_cast<float4*>(out)[i] = o;
    }
}

// ===========================================================================
extern "C" void kernel_launch(void* const* d_in, const int* in_sizes, int n_in,
                              void* d_out, int out_size, void* d_ws, size_t ws_size,
                              hipStream_t stream)
{
    const float* x    = (const float*)d_in[0];
    const int*   ei   = (const int*)  d_in[1];
    const float* ew   = (const float*)d_in[2];
    const float* eps1 = (const float*)d_in[3];
    const float* W1a  = (const float*)d_in[4];
    const float* b1a  = (const float*)d_in[5];
    const float* W1b  = (const float*)d_in[6];
    const float* b1b  = (const float*)d_in[7];
    const float* g1   = (const float*)d_in[8];
    const float* be1  = (const float*)d_in[9];
    const float* epss = (const float*)d_in[10];
    const float* Wsa  = (const float*)d_in[11];
    const float* bsa  = (const float*)d_in[12];
    const float* Wsb  = (const float*)d_in[13];
    const float* bsb  = (const float*)d_in[14];
    const float* gs   = (const float*)d_in[15];
    const float* bes  = (const float*)d_in[16];

    const int N   = in_sizes[0] / 128;
    const int E   = in_sizes[2];
    const int Lm1 = in_sizes[10];
    const int* src  = ei;
    const int* dstp = ei + E;

    // ---- workspace layout ----
    char* ws = (char*)d_ws;
    size_t off = 0;
    unsigned* einfo = (unsigned*)(ws + off); off += (size_t)E * 4;
    float* regA  = (float*)(ws + off);   off += (size_t)N * 128 * 4;
    unsigned* ybf = (unsigned*)(ws + off); off += (size_t)N * 32 * 4;
    int*   rank  = (int*)  (ws + off);   off += (size_t)E * 4;
    int*   deg   = (int*)  (ws + off);   off += (size_t)N * 4;
    int*   row_start = (int*)(ws + off); off += (size_t)(N + 1) * 4;
    float* stats3 = (float*)(ws + off);  off += 384 * 4;
    int*   blockSums = (int*)(ws + off); off += 256 * 4;
    off = (off + 15) & ~(size_t)15;
    unsigned short* wf = (unsigned short*)(ws + off);
    float* outp  = (float*)d_out;
    float* bufY  = regA;                                   // h2 scratch (N*64 f32)
    unsigned* midu = (unsigned*)(regA + (size_t)N * 64);   // [N][32] packed bf16

    const int n4   = N * 64 / 4;
    const int NB   = (N + 511) / 512;
    const int EB   = (E + 255) / 256;
    const int nW   = 6 + 4 * Lm1;
    const int PREP_B = (N + 255) / 256;
    const int NT   = (N + 63) / 64;       // one tile per block

    prep_wfrag<<<PREP_B, 256, 0, stream>>>(W1a, W1b, Wsa, Wsb, wf, deg, stats3, N, nW);

    // ---- layer-1 gemm (x @ W1a -> ybf) FUSED with CSR rank pass ----
    gemm_mfma<4, 0, true, false><<<1024 + EB, 256, 0, stream>>>(
        x, wf, nullptr, ybf, nullptr, nullptr, nullptr, nullptr, nullptr, nullptr, N,
        dstp, deg, rank, E, 1024);

    // ---- CSR scan + fill ----
    scan_part1<<<NB, 256, 0, stream>>>(deg, blockSums, N);
    scan_part3<<<NB, 256, 0, stream>>>(deg, blockSums, row_start, NB, N, E);
    fill_pass2<<<EB, 256, 0, stream>>>(src, dstp, ew, rank, row_start, einfo, E);

    // ---- layer 1 rest ----
    aggmid_kernel<<<2048, 256, 0, stream>>>(ybf, row_start, einfo, eps1, b1a, midu, N);
    gemm_mfma<2, 1, false, true><<<NT, 256, 0, stream>>>(
        midu, wf + 8192, b1b, bufY, stats3, nullptr, nullptr, nullptr, nullptr, nullptr, N,
        nullptr, nullptr, nullptr, 0, NT);

    // ---- layers 2..L: fused BN(prev)+ReLU(+res) inside Wa gemm ----
    const float* pg  = g1;
    const float* pbe = be1;
    const float* resp = nullptr;
    for (int i = 0; i < Lm1; ++i) {
        const unsigned short* wfAi = wf + 12288 + i * 8192;
        const unsigned short* wfBi = wf + 12288 + i * 8192 + 4096;
        gemm_mfma<2, 2, true, false><<<NT, 256, 0, stream>>>(
            bufY, wfAi, nullptr, ybf, nullptr, stats3 + i * 128, pg, pbe, resp, outp, N,
            nullptr, nullptr, nullptr, 0, NT);
        aggmid_kernel<<<2048, 256, 0, stream>>>(
            ybf, row_start, einfo, epss + i, bsa + (size_t)i * 64, midu, N);
        gemm_mfma<2, 1, false, true><<<NT, 256, 0, stream>>>(
            midu, wfBi, bsb + (size_t)i * 64, bufY, stats3 + (i + 1) * 128,
            nullptr, nullptr, nullptr, nullptr, nullptr, N,
            nullptr, nullptr, nullptr, 0, NT);
        pg  = gs  + (size_t)i * 64;
        pbe = bes + (size_t)i * 64;
        resp = outp;
    }

    // ---- final BN apply ----
    if (Lm1 > 0)
        bn_apply<1><<<2048, 256, 0, stream>>>(bufY, stats3 + Lm1 * 128, pg, pbe, outp, outp, N, n4);
    else
        bn_apply<0><<<2048, 256, 0, stream>>>(bufY, stats3, pg, pbe, nullptr, outp, N, n4);
}

// Round 23
// 401.192 us; speedup vs baseline: 1.3581x; 1.1280x over previous
//
#include <hip/hip_runtime.h>

#define BN_EPS 1e-5f

typedef __attribute__((ext_vector_type(8))) short bf16x8;
typedef __attribute__((ext_vector_type(4))) float f32x4;

__device__ __forceinline__ unsigned short f32_to_bf16(float f) {
    unsigned u = __float_as_uint(f);
    u += 0x7fffu + ((u >> 16) & 1u);   // round to nearest even
    return (unsigned short)(u >> 16);
}
__device__ __forceinline__ float bf16_lo(unsigned v) { return __uint_as_float(v << 16); }
__device__ __forceinline__ float bf16_hi(unsigned v) { return __uint_as_float(v & 0xffff0000u); }

#define EW_SCALE (1.0f / 32767.0f)

// ===========================================================================
// CSR construction (by dst): rank pass (fused into layer-1 gemm) ->
// scan (2 kernels) -> atomic-free fill.  einfo packed 4B: (src<<15) | ew_q15
// ===========================================================================
__global__ __launch_bounds__(256) void scan_part1(
    const int* __restrict__ deg, int* __restrict__ blockSums, int N)
{
    __shared__ int sm[256];
    int t = threadIdx.x;
    int i0 = blockIdx.x * 512 + t * 2;
    int a = (i0     < N) ? deg[i0]     : 0;
    int b = (i0 + 1 < N) ? deg[i0 + 1] : 0;
    sm[t] = a + b;
    __syncthreads();
    for (int off = 128; off > 0; off >>= 1) {
        if (t < off) sm[t] += sm[t + off];
        __syncthreads();
    }
    if (t == 0) blockSums[blockIdx.x] = sm[0];
}

__global__ __launch_bounds__(256) void scan_part3(
    const int* __restrict__ deg, const int* __restrict__ blockSums,
    int* __restrict__ row_start, int NB, int N, int E)
{
    __shared__ int sb[256];
    __shared__ int sm[256];
    int t = threadIdx.x;

    sb[t] = (t < NB) ? blockSums[t] : 0;
    __syncthreads();
    for (int off = 1; off < 256; off <<= 1) {
        int v = (t >= off) ? sb[t - off] : 0;
        __syncthreads();
        sb[t] += v;
        __syncthreads();
    }
    const int boff = (blockIdx.x > 0) ? sb[blockIdx.x - 1] : 0;

    int i0 = blockIdx.x * 512 + t * 2;
    int a = (i0     < N) ? deg[i0]     : 0;
    int b = (i0 + 1 < N) ? deg[i0 + 1] : 0;
    sm[t] = a + b;
    __syncthreads();
    for (int off = 1; off < 256; off <<= 1) {
        int v = (t >= off) ? sm[t - off] : 0;
        __syncthreads();
        sm[t] += v;
        __syncthreads();
    }
    int excl = boff + ((t > 0) ? sm[t - 1] : 0);
    if (i0 < N)     row_start[i0]     = excl;
    if (i0 + 1 < N) row_start[i0 + 1] = excl + a;
    if (blockIdx.x == 0 && t == 0) row_start[N] = E;
}

__global__ __launch_bounds__(256) void fill_pass2(
    const int* __restrict__ src, const int* __restrict__ dst,
    const float* __restrict__ ew, const int* __restrict__ rank,
    const int* __restrict__ row_start, unsigned* __restrict__ einfo, int E)
{
    int i = blockIdx.x * 256 + threadIdx.x;
    if (i < E) {
        int pos = row_start[dst[i]] + rank[i];
        unsigned q = (unsigned)__float2int_rn(ew[i] * 32767.0f);
        einfo[pos] = ((unsigned)src[i] << 15) | q;
    }
}

// ===========================================================================
// Pack weights into MFMA B-frag layout (bf16); zero-init deg and stats.
// ===========================================================================
__global__ __launch_bounds__(256) void prep_wfrag(
    const float* __restrict__ W1a, const float* __restrict__ W1b,
    const float* __restrict__ Wsa, const float* __restrict__ Wsb,
    unsigned short* __restrict__ wf, int* __restrict__ deg,
    float* __restrict__ stats3, int N, int nW)
{
    int z = blockIdx.x * 256 + threadIdx.x;
    if (z < N) deg[z] = 0;
    if (z < 384) stats3[z] = 0.f;

    int bid = blockIdx.x;
    if (bid >= nW) return;
    const float* src; unsigned short* dst; int KS, chunk;
    if (bid < 4)      { src = W1a; dst = wf;        KS = 4; chunk = bid; }
    else if (bid < 6) { src = W1b; dst = wf + 8192; KS = 2; chunk = bid - 4; }
    else {
        int t = bid - 6;
        int layer = t >> 2;
        int wh = (t >> 1) & 1;
        chunk = t & 1;
        src = (wh ? Wsb : Wsa) + (size_t)layer * 4096;
        dst = wf + 12288 + layer * 8192 + wh * 4096;
        KS = 2;
    }
    int base = chunk * 2048;
    for (int e = base + threadIdx.x; e < base + 2048; e += 256) {
        int j  = e & 7;
        int l  = (e >> 3) & 63;
        int nk = e >> 9;
        int ks = nk % KS, n = nk / KS;
        int k  = ks * 32 + ((l >> 4) << 3) + j;
        int c  = n * 16 + (l & 15);
        dst[e] = f32_to_bf16(src[k * 64 + c]);
    }
}

// ===========================================================================
// Persistent multi-tile MFMA GEMM (+ optional fused rank pass).
// GEMM blocks are blockIdx < gblocks (scheduled FIRST); rank blocks follow.
// B-fragments read from global (L2-hot). Stats in registers across tiles,
// one atomic round per block after the tile loop (chain depth = gblocks;
// keep gblocks moderate for STATS kernels — R22 lesson).
// MODE 0: A f32. MODE 1: A packed bf16. MODE 2: fused BN+ReLU(+res) staging.
// ===========================================================================
template<int KS, int MODE, bool BF16OUT, bool STATS>
__global__ __launch_bounds__(256) void gemm_mfma(
    const void* __restrict__ Ain, const unsigned short* __restrict__ wfrag,
    const float* __restrict__ bias, void* __restrict__ out,
    float* __restrict__ statsOut,
    const float* __restrict__ statsIn, const float* __restrict__ g,
    const float* __restrict__ be, const float* __restrict__ res,
    float* __restrict__ hout, int N,
    const int* __restrict__ rdst, int* __restrict__ rdeg,
    int* __restrict__ rrank, int rE, int gblocks)
{
    constexpr int K   = KS * 32;
    constexpr int LDA = K + 8;
    __shared__ __align__(16) unsigned short sA[64 * LDA];
    __shared__ float sab[128];

    const int tid = threadIdx.x;
    if ((int)blockIdx.x >= gblocks) {          // rank blocks (tail indices)
        int i = (blockIdx.x - gblocks) * 256 + tid;
        if (i < rE) rrank[i] = atomicAdd(&rdeg[rdst[i]], 1);
        return;
    }
    const int bid = blockIdx.x;

    if (MODE == 2) {
        if (tid < 64) {
            float invN = 1.0f / (float)N;
            float mean = statsIn[tid] * invN;
            float var  = statsIn[64 + tid] * invN - mean * mean;
            float a = g[tid] * rsqrtf(var + BN_EPS);
            sab[tid]      = a;
            sab[64 + tid] = be[tid] - mean * a;
        }
        __syncthreads();
    }

    const int w  = tid >> 6;
    const int l  = tid & 63;
    const int lr = l & 15;
    const int lg = l >> 4;
    const int ntiles = (N + 63) >> 6;
    const bf16x8* wg = (const bf16x8*)wfrag;

    float csAcc[4] = {0.f, 0.f, 0.f, 0.f};
    float cqAcc[4] = {0.f, 0.f, 0.f, 0.f};

    for (int tile = bid; tile < ntiles; tile += gblocks) {
        const int r0 = tile * 64;

        if (MODE == 1) {
            const uint4* Au = (const uint4*)Ain;
            constexpr int C16 = K / 8;
            for (int i = tid; i < 64 * C16; i += 256) {
                int r = i / C16, c = i % C16;
                uint4 v = make_uint4(0u, 0u, 0u, 0u);
                if (r0 + r < N) v = Au[(size_t)(r0 + r) * C16 + c];
                *reinterpret_cast<uint4*>(&sA[r * LDA + c * 8]) = v;
            }
        } else {
            const float* Af = (const float*)Ain;
            constexpr int C4 = K / 4;
            for (int i = tid; i < 64 * C4; i += 256) {
                int r = i / C4, c4 = i % C4;
                int gr = r0 + r;
                float4 v = make_float4(0.f, 0.f, 0.f, 0.f);
                if (gr < N) {
                    v = reinterpret_cast<const float4*>(Af + (size_t)gr * K)[c4];
                    if (MODE == 2) {
                        int l0 = c4 * 4;
                        v.x = fmaxf(fmaf(v.x, sab[l0 + 0], sab[64 + l0 + 0]), 0.f);
                        v.y = fmaxf(fmaf(v.y, sab[l0 + 1], sab[64 + l0 + 1]), 0.f);
                        v.z = fmaxf(fmaf(v.z, sab[l0 + 2], sab[64 + l0 + 2]), 0.f);
                        v.w = fmaxf(fmaf(v.w, sab[l0 + 3], sab[64 + l0 + 3]), 0.f);
                        if (res) {
                            float4 rv = reinterpret_cast<const float4*>(res + (size_t)gr * K)[c4];
                            v.x += rv.x; v.y += rv.y; v.z += rv.z; v.w += rv.w;
                        }
                        reinterpret_cast<float4*>(hout + (size_t)gr * K)[c4] = v;
                    }
                }
                ushort4 pk;
                pk.x = f32_to_bf16(v.x); pk.y = f32_to_bf16(v.y);
                pk.z = f32_to_bf16(v.z); pk.w = f32_to_bf16(v.w);
                *reinterpret_cast<ushort4*>(&sA[r * LDA + c4 * 4]) = pk;
            }
        }
        __syncthreads();

        f32x4 acc0 = {0.f,0.f,0.f,0.f}, acc1 = {0.f,0.f,0.f,0.f};
        f32x4 acc2 = {0.f,0.f,0.f,0.f}, acc3 = {0.f,0.f,0.f,0.f};

        #pragma unroll
        for (int ks = 0; ks < KS; ++ks) {
            bf16x8 af = *reinterpret_cast<const bf16x8*>(
                &sA[(w * 16 + lr) * LDA + ks * 32 + lg * 8]);
            bf16x8 b0 = wg[(0 * KS + ks) * 64 + l];
            bf16x8 b1 = wg[(1 * KS + ks) * 64 + l];
            bf16x8 b2 = wg[(2 * KS + ks) * 64 + l];
            bf16x8 b3 = wg[(3 * KS + ks) * 64 + l];
            acc0 = __builtin_amdgcn_mfma_f32_16x16x32_bf16(af, b0, acc0, 0, 0, 0);
            acc1 = __builtin_amdgcn_mfma_f32_16x16x32_bf16(af, b1, acc1, 0, 0, 0);
            acc2 = __builtin_amdgcn_mfma_f32_16x16x32_bf16(af, b2, acc2, 0, 0, 0);
            acc3 = __builtin_amdgcn_mfma_f32_16x16x32_bf16(af, b3, acc3, 0, 0, 0);
        }

        const int rlocal = w * 16 + lg * 4;
        float v[4][4];
        #pragma unroll
        for (int n = 0; n < 4; ++n) {
            float bv = bias ? bias[n * 16 + lr] : 0.f;
            f32x4 a = (n == 0) ? acc0 : (n == 1) ? acc1 : (n == 2) ? acc2 : acc3;
            #pragma unroll
            for (int j = 0; j < 4; ++j) {
                float vv = a[j] + bv;
                v[n][j] = vv;
                if (STATS && (r0 + rlocal + j < N)) {
                    csAcc[n] += vv; cqAcc[n] += vv * vv;
                }
            }
        }

        __syncthreads();   // all waves done reading sA

        if (BF16OUT) {
            #pragma unroll
            for (int n = 0; n < 4; ++n)
                #pragma unroll
                for (int j = 0; j < 4; ++j)
                    sA[(rlocal + j) * 72 + n * 16 + lr] = f32_to_bf16(v[n][j]);
            __syncthreads();
            unsigned short* o = (unsigned short*)out;
            for (int i = tid; i < 64 * 8; i += 256) {
                int r = i >> 3, q = i & 7;
                if (r0 + r < N)
                    *reinterpret_cast<uint4*>(o + (size_t)(r0 + r) * 64 + q * 8) =
                        *reinterpret_cast<const uint4*>(&sA[r * 72 + q * 8]);
            }
        } else {
            float* o = (float*)out;
            float* sAf = reinterpret_cast<float*>(sA);
            #pragma unroll
            for (int half = 0; half < 2; ++half) {
                if ((w >> 1) == half) {
                    #pragma unroll
                    for (int n = 0; n < 4; ++n)
                        #pragma unroll
                        for (int j = 0; j < 4; ++j)
                            sAf[((w & 1) * 16 + lg * 4 + j) * 68 + n * 16 + lr] = v[n][j];
                }
                __syncthreads();
                for (int i = tid; i < 32 * 16; i += 256) {
                    int r = i >> 4, c4 = i & 15;
                    int gr = r0 + half * 32 + r;
                    if (gr < N)
                        *reinterpret_cast<float4*>(o + (size_t)gr * 64 + c4 * 4) =
                            *reinterpret_cast<const float4*>(&sAf[r * 68 + c4 * 4]);
                }
                __syncthreads();
            }
        }
        __syncthreads();   // protect sA before next tile's staging
    }

    if (STATS) {
        float* red = reinterpret_cast<float*>(sA);
        int gg = w * 4 + lg;
        #pragma unroll
        for (int n = 0; n < 4; ++n) red[gg * 64 + n * 16 + lr] = csAcc[n];
        __syncthreads();
        if (tid < 64) {
            float s = 0.f;
            #pragma unroll
            for (int g2 = 0; g2 < 16; ++g2) s += red[g2 * 64 + tid];
            atomicAdd(&statsOut[tid], s);
        }
        __syncthreads();
        #pragma unroll
        for (int n = 0; n < 4; ++n) red[gg * 64 + n * 16 + lr] = cqAcc[n];
        __syncthreads();
        if (tid < 64) {
            float q = 0.f;
            #pragma unroll
            for (int g2 = 0; g2 < 16; ++g2) q += red[g2 * 64 + tid];
            atomicAdd(&statsOut[64 + tid], q);
        }
    }
}

// ===========================================================================
// Gather-aggregate: quarter-wave (16 lanes x uint2 = 128B) per edge,
// 16-edge unroll => 16 outstanding gathers per wave.
// ===========================================================================
__global__ __launch_bounds__(256) void aggmid_kernel(
    const unsigned* __restrict__ yu,
    const int* __restrict__ row_start,
    const unsigned* __restrict__ einfo,
    const float* __restrict__ epsp,
    const float* __restrict__ ba,
    unsigned* __restrict__ midu, int N)
{
    const int lane = threadIdx.x & 63;
    const int q    = lane >> 4;
    const int u    = lane & 15;
    int w  = (blockIdx.x * 256 + threadIdx.x) >> 6;
    const int nw = (gridDim.x * 256) >> 6;
    const float eps1 = 1.0f + epsp[0];
    const float4 bal = *reinterpret_cast<const float4*>(ba + 4 * u);

    for (int r = w; r < N; r += nw) {
        const int rs = row_start[r];
        const int re = row_start[r + 1];

        float A0=0.f,A1=0.f,A2=0.f,A3=0.f, B0=0.f,B1=0.f,B2=0.f,B3=0.f;
        float C0=0.f,C1=0.f,C2=0.f,C3=0.f, D0=0.f,D1=0.f,D2=0.f,D3=0.f;
        int j = rs;
        for (; j + 16 <= re; j += 16) {
            const int b = j + q * 4;
            unsigned p0 = einfo[b + 0], p1 = einfo[b + 1];
            unsigned p2 = einfo[b + 2], p3 = einfo[b + 3];
            uint2 y0 = *reinterpret_cast<const uint2*>(&yu[(size_t)(p0 >> 15) * 32 + 2 * u]);
            uint2 y1 = *reinterpret_cast<const uint2*>(&yu[(size_t)(p1 >> 15) * 32 + 2 * u]);
            uint2 y2 = *reinterpret_cast<const uint2*>(&yu[(size_t)(p2 >> 15) * 32 + 2 * u]);
            uint2 y3 = *reinterpret_cast<const uint2*>(&yu[(size_t)(p3 >> 15) * 32 + 2 * u]);
            float w0 = (float)(p0 & 0x7FFFu) * EW_SCALE;
            float w1 = (float)(p1 & 0x7FFFu) * EW_SCALE;
            float w2 = (float)(p2 & 0x7FFFu) * EW_SCALE;
            float w3 = (float)(p3 & 0x7FFFu) * EW_SCALE;
            A0 = fmaf(w0, bf16_lo(y0.x), A0); A1 = fmaf(w0, bf16_hi(y0.x), A1);
            A2 = fmaf(w0, bf16_lo(y0.y), A2); A3 = fmaf(w0, bf16_hi(y0.y), A3);
            B0 = fmaf(w1, bf16_lo(y1.x), B0); B1 = fmaf(w1, bf16_hi(y1.x), B1);
            B2 = fmaf(w1, bf16_lo(y1.y), B2); B3 = fmaf(w1, bf16_hi(y1.y), B3);
            C0 = fmaf(w2, bf16_lo(y2.x), C0); C1 = fmaf(w2, bf16_hi(y2.x), C1);
            C2 = fmaf(w2, bf16_lo(y2.y), C2); C3 = fmaf(w2, bf16_hi(y2.y), C3);
            D0 = fmaf(w3, bf16_lo(y3.x), D0); D1 = fmaf(w3, bf16_hi(y3.x), D1);
            D2 = fmaf(w3, bf16_lo(y3.y), D2); D3 = fmaf(w3, bf16_hi(y3.y), D3);
        }
        for (; j + 4 <= re; j += 4) {
            unsigned p = einfo[j + q];
            uint2 y = *reinterpret_cast<const uint2*>(&yu[(size_t)(p >> 15) * 32 + 2 * u]);
            float wv = (float)(p & 0x7FFFu) * EW_SCALE;
            A0 = fmaf(wv, bf16_lo(y.x), A0); A1 = fmaf(wv, bf16_hi(y.x), A1);
            A2 = fmaf(wv, bf16_lo(y.y), A2); A3 = fmaf(wv, bf16_hi(y.y), A3);
        }
        if (j < re) {
            int e = j + q;
            bool valid = e < re;
            unsigned p = einfo[valid ? e : rs];
            float wv = valid ? (float)(p & 0x7FFFu) * EW_SCALE : 0.f;
            uint2 y = *reinterpret_cast<const uint2*>(&yu[(size_t)(p >> 15) * 32 + 2 * u]);
            B0 = fmaf(wv, bf16_lo(y.x), B0); B1 = fmaf(wv, bf16_hi(y.x), B1);
            B2 = fmaf(wv, bf16_lo(y.y), B2); B3 = fmaf(wv, bf16_hi(y.y), B3);
        }
        float s0 = (A0 + B0) + (C0 + D0);
        float s1 = (A1 + B1) + (C1 + D1);
        float s2 = (A2 + B2) + (C2 + D2);
        float s3 = (A3 + B3) + (C3 + D3);
        s0 += __shfl_xor(s0, 16); s0 += __shfl_xor(s0, 32);
        s1 += __shfl_xor(s1, 16); s1 += __shfl_xor(s1, 32);
        s2 += __shfl_xor(s2, 16); s2 += __shfl_xor(s2, 32);
        s3 += __shfl_xor(s3, 16); s3 += __shfl_xor(s3, 32);

        uint2 sv = *reinterpret_cast<const uint2*>(&yu[(size_t)r * 32 + 2 * u]);
        float m0 = fmaf(eps1, bf16_lo(sv.x), s0) + bal.x;
        float m1 = fmaf(eps1, bf16_hi(sv.x), s1) + bal.y;
        float m2 = fmaf(eps1, bf16_lo(sv.y), s2) + bal.z;
        float m3 = fmaf(eps1, bf16_hi(sv.y), s3) + bal.w;
        if (q == 0) {
            uint2 pk;
            pk.x = (unsigned)f32_to_bf16(fmaxf(m0, 0.f))
                 | ((unsigned)f32_to_bf16(fmaxf(m1, 0.f)) << 16);
            pk.y = (unsigned)f32_to_bf16(fmaxf(m2, 0.f))
                 | ((unsigned)f32_to_bf16(fmaxf(m3, 0.f)) << 16);
            *reinterpret_cast<uint2*>(&midu[(size_t)r * 32 + 2 * u]) = pk;
        }
    }
}

// ===========================================================================
// Final BN apply with fused finalize (+ReLU, optional residual)
// ===========================================================================
template<int RES>
__global__ __launch_bounds__(256) void bn_apply(
    const float* __restrict__ h2, const float* __restrict__ stats,
    const float* __restrict__ g, const float* __restrict__ be,
    const float* res, float* out, int N, int n4)
{
    __shared__ float sab[128];
    int t = threadIdx.x;
    if (t < 64) {
        float invN = 1.0f / (float)N;
        float mean = stats[t] * invN;
        float var  = stats[64 + t] * invN - mean * mean;
        float a = g[t] * rsqrtf(var + BN_EPS);
        sab[t]      = a;
        sab[64 + t] = be[t] - mean * a;
    }
    __syncthreads();

    int i = blockIdx.x * blockDim.x + t;
    int stride = gridDim.x * blockDim.x;
    for (; i < n4; i += stride) {
        float4 v = reinterpret_cast<const float4*>(h2)[i];
        int l0 = (i * 4) & 63;
        float4 o;
        o.x = fmaxf(fmaf(v.x, sab[l0 + 0], sab[64 + l0 + 0]), 0.f);
        o.y = fmaxf(fmaf(v.y, sab[l0 + 1], sab[64 + l0 + 1]), 0.f);
        o.z = fmaxf(fmaf(v.z, sab[l0 + 2], sab[64 + l0 + 2]), 0.f);
        o.w = fmaxf(fmaf(v.w, sab[l0 + 3], sab[64 + l0 + 3]), 0.f);
        if (RES) {
            float4 rv = reinterpret_cast<const float4*>(res)[i];
            o.x += rv.x; o.y += rv.y; o.z += rv.z; o.w += rv.w;
        }
        reinterpret_cast<float4*>(out)[i] = o;
    }
}

// ===========================================================================
extern "C" void kernel_launch(void* const* d_in, const int* in_sizes, int n_in,
                              void* d_out, int out_size, void* d_ws, size_t ws_size,
                              hipStream_t stream)
{
    const float* x    = (const float*)d_in[0];
    const int*   ei   = (const int*)  d_in[1];
    const float* ew   = (const float*)d_in[2];
    const float* eps1 = (const float*)d_in[3];
    const float* W1a  = (const float*)d_in[4];
    const float* b1a  = (const float*)d_in[5];
    const float* W1b  = (const float*)d_in[6];
    const float* b1b  = (const float*)d_in[7];
    const float* g1   = (const float*)d_in[8];
    const float* be1  = (const float*)d_in[9];
    const float* epss = (const float*)d_in[10];
    const float* Wsa  = (const float*)d_in[11];
    const float* bsa  = (const float*)d_in[12];
    const float* Wsb  = (const float*)d_in[13];
    const float* bsb  = (const float*)d_in[14];
    const float* gs   = (const float*)d_in[15];
    const float* bes  = (const float*)d_in[16];

    const int N   = in_sizes[0] / 128;
    const int E   = in_sizes[2];
    const int Lm1 = in_sizes[10];
    const int* src  = ei;
    const int* dstp = ei + E;

    // ---- workspace layout ----
    char* ws = (char*)d_ws;
    size_t off = 0;
    unsigned* einfo = (unsigned*)(ws + off); off += (size_t)E * 4;
    float* regA  = (float*)(ws + off);   off += (size_t)N * 128 * 4;
    unsigned* ybf = (unsigned*)(ws + off); off += (size_t)N * 32 * 4;
    int*   rank  = (int*)  (ws + off);   off += (size_t)E * 4;
    int*   deg   = (int*)  (ws + off);   off += (size_t)N * 4;
    int*   row_start = (int*)(ws + off); off += (size_t)(N + 1) * 4;
    float* stats3 = (float*)(ws + off);  off += 384 * 4;
    int*   blockSums = (int*)(ws + off); off += 256 * 4;
    off = (off + 15) & ~(size_t)15;
    unsigned short* wf = (unsigned short*)(ws + off);
    float* outp  = (float*)d_out;
    float* bufY  = regA;                                   // h2 scratch (N*64 f32)
    unsigned* midu = (unsigned*)(regA + (size_t)N * 64);   // [N][32] packed bf16

    const int n4   = N * 64 / 4;
    const int NB   = (N + 511) / 512;
    const int EB   = (E + 255) / 256;
    const int nW   = 6 + 4 * Lm1;
    const int PREP_B = (N + 255) / 256;
    const int NT   = (N + 63) / 64;       // one tile per block (MODE2 gemms)
    const int GBS  = 1024;                // persistent blocks for STATS gemms

    prep_wfrag<<<PREP_B, 256, 0, stream>>>(W1a, W1b, Wsa, Wsb, wf, deg, stats3, N, nW);

    // ---- layer-1 gemm (x @ W1a -> ybf) FUSED with CSR rank pass ----
    gemm_mfma<4, 0, true, false><<<1024 + EB, 256, 0, stream>>>(
        x, wf, nullptr, ybf, nullptr, nullptr, nullptr, nullptr, nullptr, nullptr, N,
        dstp, deg, rank, E, 1024);

    // ---- CSR scan + fill ----
    scan_part1<<<NB, 256, 0, stream>>>(deg, blockSums, N);
    scan_part3<<<NB, 256, 0, stream>>>(deg, blockSums, row_start, NB, N, E);
    fill_pass2<<<EB, 256, 0, stream>>>(src, dstp, ew, rank, row_start, einfo, E);

    // ---- layer 1 rest ----
    aggmid_kernel<<<2048, 256, 0, stream>>>(ybf, row_start, einfo, eps1, b1a, midu, N);
    gemm_mfma<2, 1, false, true><<<GBS, 256, 0, stream>>>(
        midu, wf + 8192, b1b, bufY, stats3, nullptr, nullptr, nullptr, nullptr, nullptr, N,
        nullptr, nullptr, nullptr, 0, GBS);

    // ---- layers 2..L: fused BN(prev)+ReLU(+res) inside Wa gemm ----
    const float* pg  = g1;
    const float* pbe = be1;
    const float* resp = nullptr;
    for (int i = 0; i < Lm1; ++i) {
        const unsigned short* wfAi = wf + 12288 + i * 8192;
        const unsigned short* wfBi = wf + 12288 + i * 8192 + 4096;
        gemm_mfma<2, 2, true, false><<<NT, 256, 0, stream>>>(
            bufY, wfAi, nullptr, ybf, nullptr, stats3 + i * 128, pg, pbe, resp, outp, N,
            nullptr, nullptr, nullptr, 0, NT);
        aggmid_kernel<<<2048, 256, 0, stream>>>(
            ybf, row_start, einfo, epss + i, bsa + (size_t)i * 64, midu, N);
        gemm_mfma<2, 1, false, true><<<GBS, 256, 0, stream>>>(
            midu, wfBi, bsb + (size_t)i * 64, bufY, stats3 + (i + 1) * 128,
            nullptr, nullptr, nullptr, nullptr, nullptr, N,
            nullptr, nullptr, nullptr, 0, GBS);
        pg  = gs  + (size_t)i * 64;
        pbe = bes + (size_t)i * 64;
        resp = outp;
    }

    // ---- final BN apply ----
    if (Lm1 > 0)
        bn_apply<1><<<2048, 256, 0, stream>>>(bufY, stats3 + Lm1 * 128, pg, pbe, outp, outp, N, n4);
    else
        bn_apply<0><<<2048, 256, 0, stream>>>(bufY, stats3, pg, pbe, nullptr, outp, N, n4);
}